// Round 7
// baseline (1470.174 us; speedup 1.0000x reference)
//
#include <hip/hip_runtime.h>
#include <hip/hip_bf16.h>
#include <cstdint>

#define HID 2048
#define FFN 4096
#define NE 16
#define NTOK 2048
#define TOPK 4
#define BM 256
#define BN 64
#define BK 64
#define MAXT 48
#define TOTROWS 8192
#define GRID1 (MAXT * (FFN / BN))   // 3072
#define GRID2 (MAXT * (HID / BN))   // 1536
#define CHUNK1 (GRID1 / 8)
#define CHUNK2 (GRID2 / 8)
#define NT1 (HID / BK)              // 32
#define NT2 (FFN / BK)              // 64

typedef __attribute__((ext_vector_type(4))) float f32x4;
typedef __attribute__((ext_vector_type(8))) short bf16x8;

__device__ __forceinline__ ushort f2bf(float f) {
  __hip_bfloat16 h = __float2bfloat16(f);
  return *reinterpret_cast<ushort*>(&h);
}

__device__ __forceinline__ float bf2f(ushort u) {
  unsigned int v = ((unsigned int)u) << 16;
  return *reinterpret_cast<float*>(&v);
}

__device__ __forceinline__ int swz(int row) { return (row ^ (row >> 2)) & 7; }

__device__ __forceinline__ void gload_lds16(const void* g, void* l) {
  __builtin_amdgcn_global_load_lds((const __attribute__((address_space(1))) void*)g,
                                   (__attribute__((address_space(3))) void*)l, 16, 0, 0);
}

// raw barrier with compiler-level memory fences (no sched_barrier, no vmcnt drain)
__device__ __forceinline__ void wgbar() {
  asm volatile("" ::: "memory");
  __builtin_amdgcn_s_barrier();
  asm volatile("" ::: "memory");
}

// ---------------- init ----------------
__global__ void init_kernel(int* __restrict__ counts) {
  if (threadIdx.x < NE) counts[threadIdx.x] = 0;
}

// ---------------- x -> bf16 ----------------
__global__ void cvt_x_kernel(const float* __restrict__ x, ushort* __restrict__ xbf) {
  int i = blockIdx.x * 256 + threadIdx.x;
  float4 v = ((const float4*)x)[i];
  ushort4 o;
  o.x = f2bf(v.x); o.y = f2bf(v.y); o.z = f2bf(v.z); o.w = f2bf(v.w);
  ((ushort4*)xbf)[i] = o;
}

// ---------------- router ----------------
__global__ void router_kernel(const float* __restrict__ x, const float* __restrict__ rw,
                              float* __restrict__ wout, float* __restrict__ combine,
                              int* __restrict__ counts) {
  int t = blockIdx.x;
  int tid = threadIdx.x, lane = tid & 63, w = tid >> 6;
  const float* xr = x + (size_t)t * HID;
  const float* r0 = rw + (size_t)(w * 4 + 0) * HID;
  const float* r1 = rw + (size_t)(w * 4 + 1) * HID;
  const float* r2 = rw + (size_t)(w * 4 + 2) * HID;
  const float* r3 = rw + (size_t)(w * 4 + 3) * HID;
  float s0 = 0.f, s1 = 0.f, s2 = 0.f, s3 = 0.f;
  for (int h = lane; h < HID; h += 64) {
    float xv = xr[h];
    s0 += xv * r0[h]; s1 += xv * r1[h]; s2 += xv * r2[h]; s3 += xv * r3[h];
  }
  #pragma unroll
  for (int off = 32; off > 0; off >>= 1) {
    s0 += __shfl_down(s0, off); s1 += __shfl_down(s1, off);
    s2 += __shfl_down(s2, off); s3 += __shfl_down(s3, off);
  }
  __shared__ float logits[NE];
  if (lane == 0) {
    logits[w * 4 + 0] = s0; logits[w * 4 + 1] = s1;
    logits[w * 4 + 2] = s2; logits[w * 4 + 3] = s3;
  }
  __syncthreads();
  if (tid == 0) {
    float p[NE];
    float mx = logits[0];
    #pragma unroll
    for (int e = 1; e < NE; e++) mx = fmaxf(mx, logits[e]);
    float ssum = 0.f;
    #pragma unroll
    for (int e = 0; e < NE; e++) { p[e] = expf(logits[e] - mx); ssum += p[e]; }
    float inv = 1.0f / ssum;
    #pragma unroll
    for (int e = 0; e < NE; e++) { p[e] *= inv; wout[t * NE + e] = p[e]; }
    int sel[TOPK]; float selw[TOPK];
    unsigned used = 0;
    for (int k = 0; k < TOPK; k++) {
      int best = 0; float bw = -1.0f;
      for (int e = 0; e < NE; e++)
        if (!((used >> e) & 1u) && p[e] > bw) { bw = p[e]; best = e; }
      used |= 1u << best; sel[k] = best; selw[k] = bw;
    }
    float sw = selw[0] + selw[1] + selw[2] + selw[3];
    float invs = 1.0f / sw;
    float comb[NE];
    #pragma unroll
    for (int e = 0; e < NE; e++) comb[e] = 0.f;
    for (int k = 0; k < TOPK; k++) comb[sel[k]] = selw[k] * invs;
    #pragma unroll
    for (int e = 0; e < NE; e++) combine[t * NE + e] = comb[e];
    for (int k = 0; k < TOPK; k++) atomicAdd(&counts[sel[k]], 1);
  }
}

// ---------------- tiles (BM=256) ----------------
__global__ void build_tiles_kernel(const int* __restrict__ counts, int* __restrict__ seg_off,
                                   int* __restrict__ tiles, int* __restrict__ ntiles) {
  if (blockIdx.x != 0 || threadIdx.x != 0) return;
  int off = 0, nt = 0;
  for (int e = 0; e < NE; e++) {
    seg_off[e] = off;
    int c = counts[e];
    for (int rb = 0; rb * BM < c; rb++) {
      tiles[nt * 3 + 0] = e;
      tiles[nt * 3 + 1] = off + rb * BM;
      tiles[nt * 3 + 2] = (c - rb * BM < BM) ? (c - rb * BM) : BM;
      nt++;
    }
    off += c;
  }
  seg_off[NE] = off;
  *ntiles = nt;
}

// ---------------- token assignment (+ deterministic token->slot map) ----------------
__global__ void assign_kernel(const float* __restrict__ combine, const int* __restrict__ seg_off,
                              int* __restrict__ token_flat, float* __restrict__ gate_flat,
                              int* __restrict__ tok_pos) {
  int e = blockIdx.x;
  int tid = threadIdx.x, lane = tid & 63, w = tid >> 6;
  __shared__ int base;
  __shared__ int wtot[4];
  if (tid == 0) base = seg_off[e];
  __syncthreads();
  for (int t0 = 0; t0 < NTOK; t0 += 256) {
    int t = t0 + tid;
    float g = combine[t * NE + e];
    int flag = (g > 0.0f) ? 1 : 0;
    unsigned long long m = __ballot(flag);
    if (lane == 0) wtot[w] = __popcll(m);
    __syncthreads();
    int pre = 0;
    for (int j = 0; j < w; j++) pre += wtot[j];
    int tot = wtot[0] + wtot[1] + wtot[2] + wtot[3];
    int lp = __popcll(m & ((1ull << lane) - 1ull));
    if (flag) {
      int pos = base + pre + lp;
      token_flat[pos] = t;
      gate_flat[pos] = g;
      int slot = 0;
      for (int e2 = 0; e2 < e; e2++) slot += (combine[t * NE + e2] > 0.0f) ? 1 : 0;
      if (slot < TOPK) tok_pos[t * TOPK + slot] = pos;
    }
    __syncthreads();
    if (tid == 0) base += tot;
    __syncthreads();
  }
}

// ---------------- GEMM1 fused: G = silu(X w1) * (X v1)  [counted-vmcnt pipeline] ----------------
__global__ __launch_bounds__(512, 4) void mlp1_kernel(
    const ushort* __restrict__ xbf, const float* __restrict__ w1, const float* __restrict__ v1,
    const int* __restrict__ tiles, const int* __restrict__ ntiles,
    const int* __restrict__ token_flat, ushort* __restrict__ G) {
  int id = blockIdx.x;
  int wg = (id & 7) * CHUNK1 + (id >> 3);
  int tile = wg % MAXT, nblk = wg / MAXT;
  if (tile >= *ntiles) return;
  const int e  = tiles[tile * 3 + 0];
  const int g0 = tiles[tile * 3 + 1];
  const int nr = tiles[tile * 3 + 2];
  const int n0 = nblk * BN;

  __shared__ __align__(16) ushort As[2][BM * BK];  // 2 x 32 KB
  __shared__ __align__(16) ushort Bw[BN * BK];     // 8 KB
  __shared__ __align__(16) ushort Bv[BN * BK];     // 8 KB

  const int tid = threadIdx.x, lane = tid & 63, wv = tid >> 6;
  const int wr = wv >> 1, wc = wv & 1;
  const int fr = lane & 15, fq = lane >> 4;

  uint aoff[4];
  int aslot[4];
  #pragma unroll
  for (int i = 0; i < 4; i++) {
    int slot = i * 512 + tid;
    int m = slot >> 3, g = slot & 7;
    int r = m < nr ? m : (nr - 1);
    int tok = token_flat[g0 + r];
    aoff[i] = (uint)(tok * HID + ((g ^ swz(m)) << 3));
    aslot[i] = slot * 8;
  }

  const int bs = tid & 255;
  const int bnq = bs & 15, bkq = bs >> 4;
  const float* bsrc = ((tid >> 8) ? v1 : w1) + (size_t)e * HID * FFN + (size_t)(bkq * 4) * FFN + n0 + bnq * 4;
  ushort* bdst = (tid >> 8) ? Bv : Bw;
  uint boff[4];
  #pragma unroll
  for (int c = 0; c < 4; c++) {
    int n = bnq * 4 + c;
    boff[c] = (uint)(n * 128 + (((bkq >> 1) ^ swz(n)) << 4) + ((bkq & 1) << 3));
  }

  float4 br0, br1, br2, br3;
  #define LOADB(k0) { size_t kb = (size_t)(k0) * FFN; \
      br0 = *(const float4*)(bsrc + kb); br1 = *(const float4*)(bsrc + kb + FFN); \
      br2 = *(const float4*)(bsrc + kb + 2 * FFN); br3 = *(const float4*)(bsrc + kb + 3 * FFN); }
  #define WRITEB() { const float* rr[4] = {(const float*)&br0, (const float*)&br1, (const float*)&br2, (const float*)&br3}; \
      _Pragma("unroll") for (int c = 0; c < 4; c++) { \
        union { ushort u[4]; uint2 v; } p; \
        _Pragma("unroll") for (int j = 0; j < 4; j++) p.u[j] = f2bf(rr[j][c]); \
        *(uint2*)((char*)bdst + boff[c]) = p.v; } }

  f32x4 acc_h[4][2] = {};
  f32x4 acc_v[4][2] = {};

  #define COMPUTE1(bi) { \
    const char* Ab = (const char*)&As[bi][0]; \
    _Pragma("unroll") \
    for (int hk = 0; hk < 2; hk++) { \
      bf16x8 af[4], bwf[2], bvf[2]; \
      _Pragma("unroll") \
      for (int am = 0; am < 4; am++) { \
        int m = wr * 64 + am * 16 + fr; \
        af[am] = *(const bf16x8*)(Ab + m * 128 + (((hk * 4 + fq) ^ swz(m)) << 4)); \
      } \
      _Pragma("unroll") \
      for (int an = 0; an < 2; an++) { \
        int n = wc * 32 + an * 16 + fr; \
        int off = n * 128 + (((hk * 4 + fq) ^ swz(n)) << 4); \
        bwf[an] = *(const bf16x8*)((const char*)Bw + off); \
        bvf[an] = *(const bf16x8*)((const char*)Bv + off); \
      } \
      __builtin_amdgcn_s_setprio(1); \
      _Pragma("unroll") \
      for (int am = 0; am < 4; am++) \
        _Pragma("unroll") \
        for (int an = 0; an < 2; an++) { \
          acc_h[am][an] = __builtin_amdgcn_mfma_f32_16x16x32_bf16(af[am], bwf[an], acc_h[am][an], 0, 0, 0); \
          acc_v[am][an] = __builtin_amdgcn_mfma_f32_16x16x32_bf16(af[am], bvf[an], acc_v[am][an], 0, 0, 0); \
        } \
      __builtin_amdgcn_s_setprio(0); \
    } \
  }

  // prologue: B(0) + A(0); WRITEB(0) (compiler counted-wait retires B(0) only); barrier
  LOADB(0);
  #pragma unroll
  for (int i = 0; i < 4; i++) gload_lds16(xbf + aoff[i], &As[0][aslot[i]]);
  WRITEB();
  asm volatile("s_waitcnt lgkmcnt(0)" ::: "memory");
  wgbar();
  // pipeline state entering t=0: A(0) DMA in flight (retired by loop's vmcnt(8))

  for (int t = 0; t < NT1 - 1; ++t) {
    const int kn = (t + 1) * BK;
    LOADB(kn);                              // B(t+1): 4 loads
    {
      ushort* abase = &As[(t + 1) & 1][0];
      #pragma unroll
      for (int i = 0; i < 4; i++) gload_lds16(xbf + aoff[i] + kn, abase + aslot[i]);  // A(t+1): 4
    }
    // retire A(t) (oldest 4); keep B(t+1)+A(t+1) = 8 in flight
    asm volatile("s_waitcnt vmcnt(8)" ::: "memory");
    wgbar();                                // #1: As[t&1] + Bw/Bv ready for all waves
    COMPUTE1(t & 1);                        // covers B(t+1)/A(t+1) latency
    asm volatile("s_waitcnt lgkmcnt(0)" ::: "memory");  // my ds_reads landed in regs
    wgbar();                                // #2: all waves done reading Bw/Bv
    WRITEB();                               // compiler counted-wait retires B(t+1); A(t+1) stays
    asm volatile("s_waitcnt lgkmcnt(0)" ::: "memory");
    wgbar();                                // #3: B(t+1) visible in LDS
  }
  // last tile: only A(NT1-1) DMA outstanding
  asm volatile("s_waitcnt vmcnt(0)" ::: "memory");
  wgbar();
  COMPUTE1((NT1 - 1) & 1);

  // epilogue: G = silu(h) * v
  #pragma unroll
  for (int am = 0; am < 4; am++) {
    #pragma unroll
    for (int j = 0; j < 4; j++) {
      int m = wr * 64 + am * 16 + fq * 4 + j;
      if (m < nr) {
        ushort* grow = G + (size_t)(g0 + m) * FFN + n0 + wc * 32 + fr;
        #pragma unroll
        for (int an = 0; an < 2; an++) {
          float h = acc_h[am][an][j];
          float v = acc_v[am][an][j];
          float g = h / (1.0f + __expf(-h)) * v;
          grow[an * 16] = f2bf(g);
        }
      }
    }
  }
  #undef LOADB
  #undef WRITEB
  #undef COMPUTE1
}

// ---------------- GEMM2: yscr = gate * (G w2)  [counted-vmcnt pipeline] ----------------
__global__ __launch_bounds__(512, 4) void mlp2_kernel(
    const ushort* __restrict__ G, const float* __restrict__ w2,
    const int* __restrict__ tiles, const int* __restrict__ ntiles,
    const float* __restrict__ gate_flat, ushort* __restrict__ yscr) {
  int id = blockIdx.x;
  int wg = (id & 7) * CHUNK2 + (id >> 3);
  int tile = wg % MAXT, nblk = wg / MAXT;
  if (tile >= *ntiles) return;
  const int e  = tiles[tile * 3 + 0];
  const int g0 = tiles[tile * 3 + 1];
  const int nr = tiles[tile * 3 + 2];
  const int n0 = nblk * BN;

  __shared__ __align__(16) ushort As[2][BM * BK];  // 2 x 32 KB
  __shared__ __align__(16) ushort Bs[BN * BK];     // 8 KB

  const int tid = threadIdx.x, lane = tid & 63, wv = tid >> 6;
  const int wr = wv >> 1, wc = wv & 1;
  const int fr = lane & 15, fq = lane >> 4;

  uint aoff[4];
  int aslot[4];
  #pragma unroll
  for (int i = 0; i < 4; i++) {
    int slot = i * 512 + tid;
    int m = slot >> 3, g = slot & 7;
    int r = m < nr ? m : (nr - 1);
    aoff[i] = (uint)((g0 + r) * FFN + ((g ^ swz(m)) << 3));
    aslot[i] = slot * 8;
  }

  const int bnq = tid & 15, bkq2 = tid >> 4;
  const float* bsrc = w2 + (size_t)e * FFN * HID + (size_t)(bkq2 * 2) * HID + n0 + bnq * 4;
  uint boff[4];
  #pragma unroll
  for (int c = 0; c < 4; c++) {
    int n = bnq * 4 + c;
    int k = bkq2 * 2;
    boff[c] = (uint)(n * 128 + (((k >> 3) ^ swz(n)) << 4) + ((k & 7) << 1));
  }

  float4 br0, br1;
  #define LOADB2(k0) { size_t kb = (size_t)(k0) * HID; \
      br0 = *(const float4*)(bsrc + kb); br1 = *(const float4*)(bsrc + kb + HID); }
  #define WRITEB2() { const float* rr[2] = {(const float*)&br0, (const float*)&br1}; \
      _Pragma("unroll") for (int c = 0; c < 4; c++) { \
        union { ushort u[2]; uint v; } p; \
        p.u[0] = f2bf(rr[0][c]); p.u[1] = f2bf(rr[1][c]); \
        *(uint*)((char*)Bs + boff[c]) = p.v; } }

  f32x4 acc[4][2] = {};

  #define COMPUTE2(bi) { \
    const char* Ab = (const char*)&As[bi][0]; \
    _Pragma("unroll") \
    for (int hk = 0; hk < 2; hk++) { \
      bf16x8 af[4], bf_[2]; \
      _Pragma("unroll") \
      for (int am = 0; am < 4; am++) { \
        int m = wr * 64 + am * 16 + fr; \
        af[am] = *(const bf16x8*)(Ab + m * 128 + (((hk * 4 + fq) ^ swz(m)) << 4)); \
      } \
      _Pragma("unroll") \
      for (int an = 0; an < 2; an++) { \
        int n = wc * 32 + an * 16 + fr; \
        bf_[an] = *(const bf16x8*)((const char*)Bs + n * 128 + (((hk * 4 + fq) ^ swz(n)) << 4)); \
      } \
      __builtin_amdgcn_s_setprio(1); \
      _Pragma("unroll") \
      for (int am = 0; am < 4; am++) \
        _Pragma("unroll") \
        for (int an = 0; an < 2; an++) \
          acc[am][an] = __builtin_amdgcn_mfma_f32_16x16x32_bf16(af[am], bf_[an], acc[am][an], 0, 0, 0); \
      __builtin_amdgcn_s_setprio(0); \
    } \
  }

  LOADB2(0);
  #pragma unroll
  for (int i = 0; i < 4; i++) gload_lds16(G + aoff[i], &As[0][aslot[i]]);
  WRITEB2();
  asm volatile("s_waitcnt lgkmcnt(0)" ::: "memory");
  wgbar();

  for (int t = 0; t < NT2 - 1; ++t) {
    const int kn = (t + 1) * BK;
    LOADB2(kn);                             // B(t+1): 2 loads
    {
      ushort* abase = &As[(t + 1) & 1][0];
      #pragma unroll
      for (int i = 0; i < 4; i++) gload_lds16(G + aoff[i] + kn, abase + aslot[i]);  // A(t+1): 4
    }
    asm volatile("s_waitcnt vmcnt(6)" ::: "memory");  // retire A(t); keep B(t+1)[2]+A(t+1)[4]
    wgbar();                                // #1
    COMPUTE2(t & 1);
    asm volatile("s_waitcnt lgkmcnt(0)" ::: "memory");
    wgbar();                                // #2
    WRITEB2();
    asm volatile("s_waitcnt lgkmcnt(0)" ::: "memory");
    wgbar();                                // #3
  }
  asm volatile("s_waitcnt vmcnt(0)" ::: "memory");
  wgbar();
  COMPUTE2((NT2 - 1) & 1);

  #pragma unroll
  for (int am = 0; am < 4; am++) {
    #pragma unroll
    for (int j = 0; j < 4; j++) {
      int m = wr * 64 + am * 16 + fq * 4 + j;
      if (m < nr) {
        float gate = gate_flat[g0 + m];
        ushort* yrow = yscr + (size_t)(g0 + m) * HID + n0 + wc * 32 + fr;
        #pragma unroll
        for (int an = 0; an < 2; an++)
          yrow[an * 16] = f2bf(acc[am][an][j] * gate);
      }
    }
  }
  #undef LOADB2
  #undef WRITEB2
  #undef COMPUTE2
}

// ---------------- combine: out[t] = sum_k yscr[tok_pos[t][k]] ----------------
__global__ void combine_kernel(const ushort* __restrict__ yscr, const int* __restrict__ tok_pos,
                               float* __restrict__ out) {
  int t = blockIdx.x, tid = threadIdx.x;
  int c0 = tid * 8;
  float s[8] = {0.f, 0.f, 0.f, 0.f, 0.f, 0.f, 0.f, 0.f};
  #pragma unroll
  for (int k = 0; k < TOPK; k++) {
    int pos = tok_pos[t * TOPK + k];
    if (pos >= 0 && pos < TOTROWS) {
      const ushort4* yr = (const ushort4*)(yscr + (size_t)pos * HID + c0);
      ushort4 a = yr[0], b = yr[1];
      s[0] += bf2f(a.x); s[1] += bf2f(a.y); s[2] += bf2f(a.z); s[3] += bf2f(a.w);
      s[4] += bf2f(b.x); s[5] += bf2f(b.y); s[6] += bf2f(b.z); s[7] += bf2f(b.w);
    }
  }
  float4* op = (float4*)(out + (size_t)t * HID + c0);
  float4 o0 = {s[0], s[1], s[2], s[3]};
  float4 o1 = {s[4], s[5], s[6], s[7]};
  op[0] = o0; op[1] = o1;
}

// ---------------- launch ----------------
extern "C" void kernel_launch(void* const* d_in, const int* in_sizes, int n_in,
                              void* d_out, int out_size, void* d_ws, size_t ws_size,
                              hipStream_t stream) {
  const float* x  = (const float*)d_in[0];
  const float* rw = (const float*)d_in[1];
  const float* w1 = (const float*)d_in[2];
  const float* v1 = (const float*)d_in[3];
  const float* w2 = (const float*)d_in[4];
  float* out0 = (float*)d_out;
  float* wout = out0 + (size_t)NTOK * HID;

  char* ws = (char*)d_ws;
  float* combine    = (float*)(ws + 0);
  int*   counts     = (int*)(ws + 131072);
  int*   seg_off    = (int*)(ws + 131200);
  int*   ntiles     = (int*)(ws + 131328);
  int*   tiles      = (int*)(ws + 131392);
  int*   token_flat = (int*)(ws + 132352);
  float* gate_flat  = (float*)(ws + 165120);
  int*   tok_pos    = (int*)(ws + 197888);
  ushort* G         = (ushort*)(ws + 262144);                               // 64 MB
  ushort* xbf       = (ushort*)(ws + 262144 + (size_t)TOTROWS * FFN * 2);   // 8 MB
  ushort* yscr      = (ushort*)(ws + 262144 + (size_t)TOTROWS * FFN * 2
                                 + (size_t)NTOK * HID * 2);                 // 32 MB

  init_kernel<<<1, 64, 0, stream>>>(counts);
  cvt_x_kernel<<<(NTOK * HID / 4) / 256, 256, 0, stream>>>(x, (ushort*)xbf);
  router_kernel<<<NTOK, 256, 0, stream>>>(x, rw, wout, combine, counts);
  build_tiles_kernel<<<1, 1, 0, stream>>>(counts, seg_off, tiles, ntiles);
  assign_kernel<<<NE, 256, 0, stream>>>(combine, seg_off, token_flat, gate_flat, tok_pos);
  mlp1_kernel<<<GRID1, 512, 0, stream>>>(xbf, w1, v1, tiles, ntiles, token_flat, G);
  mlp2_kernel<<<GRID2, 512, 0, stream>>>(G, w2, tiles, ntiles, gate_flat, yscr);
  combine_kernel<<<NTOK, 256, 0, stream>>>(yscr, tok_pos, out0);
}

// Round 8
// 903.222 us; speedup vs baseline: 1.6277x; 1.6277x over previous
//
#include <hip/hip_runtime.h>
#include <hip/hip_bf16.h>
#include <cstdint>

#define HID 2048
#define FFN 4096
#define NE 16
#define NTOK 2048
#define TOPK 4
#define BM 256
#define BN 64
#define BN2 128
#define BK 64
#define MAXT 48
#define TOTROWS 8192
#define GRID1 (MAXT * (FFN / BN))    // 3072
#define GRID2 (MAXT * (HID / BN2))   // 768
#define CHUNK1 (GRID1 / 8)
#define CHUNK2 (GRID2 / 8)

typedef __attribute__((ext_vector_type(4))) float f32x4;
typedef __attribute__((ext_vector_type(8))) short bf16x8;

__device__ __forceinline__ ushort f2bf(float f) {
  __hip_bfloat16 h = __float2bfloat16(f);
  return *reinterpret_cast<ushort*>(&h);
}

__device__ __forceinline__ float bf2f(ushort u) {
  unsigned int v = ((unsigned int)u) << 16;
  return *reinterpret_cast<float*>(&v);
}

__device__ __forceinline__ int swz(int row) { return (row ^ (row >> 2)) & 7; }

__device__ __forceinline__ void gload_lds16(const void* g, void* l) {
  __builtin_amdgcn_global_load_lds((const __attribute__((address_space(1))) void*)g,
                                   (__attribute__((address_space(3))) void*)l, 16, 0, 0);
}

// ---------------- init ----------------
__global__ void init_kernel(int* __restrict__ counts) {
  if (threadIdx.x < NE) counts[threadIdx.x] = 0;
}

// ---------------- x -> bf16 ----------------
__global__ void cvt_x_kernel(const float* __restrict__ x, ushort* __restrict__ xbf) {
  int i = blockIdx.x * 256 + threadIdx.x;
  float4 v = ((const float4*)x)[i];
  ushort4 o;
  o.x = f2bf(v.x); o.y = f2bf(v.y); o.z = f2bf(v.z); o.w = f2bf(v.w);
  ((ushort4*)xbf)[i] = o;
}

// ---------------- router ----------------
__global__ void router_kernel(const float* __restrict__ x, const float* __restrict__ rw,
                              float* __restrict__ wout, float* __restrict__ combine,
                              int* __restrict__ counts) {
  int t = blockIdx.x;
  int tid = threadIdx.x, lane = tid & 63, w = tid >> 6;
  const float* xr = x + (size_t)t * HID;
  const float* r0 = rw + (size_t)(w * 4 + 0) * HID;
  const float* r1 = rw + (size_t)(w * 4 + 1) * HID;
  const float* r2 = rw + (size_t)(w * 4 + 2) * HID;
  const float* r3 = rw + (size_t)(w * 4 + 3) * HID;
  float s0 = 0.f, s1 = 0.f, s2 = 0.f, s3 = 0.f;
  for (int h = lane; h < HID; h += 64) {
    float xv = xr[h];
    s0 += xv * r0[h]; s1 += xv * r1[h]; s2 += xv * r2[h]; s3 += xv * r3[h];
  }
  #pragma unroll
  for (int off = 32; off > 0; off >>= 1) {
    s0 += __shfl_down(s0, off); s1 += __shfl_down(s1, off);
    s2 += __shfl_down(s2, off); s3 += __shfl_down(s3, off);
  }
  __shared__ float logits[NE];
  if (lane == 0) {
    logits[w * 4 + 0] = s0; logits[w * 4 + 1] = s1;
    logits[w * 4 + 2] = s2; logits[w * 4 + 3] = s3;
  }
  __syncthreads();
  if (tid == 0) {
    float p[NE];
    float mx = logits[0];
    #pragma unroll
    for (int e = 1; e < NE; e++) mx = fmaxf(mx, logits[e]);
    float ssum = 0.f;
    #pragma unroll
    for (int e = 0; e < NE; e++) { p[e] = expf(logits[e] - mx); ssum += p[e]; }
    float inv = 1.0f / ssum;
    #pragma unroll
    for (int e = 0; e < NE; e++) { p[e] *= inv; wout[t * NE + e] = p[e]; }
    int sel[TOPK]; float selw[TOPK];
    unsigned used = 0;
    for (int k = 0; k < TOPK; k++) {
      int best = 0; float bw = -1.0f;
      for (int e = 0; e < NE; e++)
        if (!((used >> e) & 1u) && p[e] > bw) { bw = p[e]; best = e; }
      used |= 1u << best; sel[k] = best; selw[k] = bw;
    }
    float sw = selw[0] + selw[1] + selw[2] + selw[3];
    float invs = 1.0f / sw;
    float comb[NE];
    #pragma unroll
    for (int e = 0; e < NE; e++) comb[e] = 0.f;
    for (int k = 0; k < TOPK; k++) comb[sel[k]] = selw[k] * invs;
    #pragma unroll
    for (int e = 0; e < NE; e++) combine[t * NE + e] = comb[e];
    for (int k = 0; k < TOPK; k++) atomicAdd(&counts[sel[k]], 1);
  }
}

// ---------------- tiles (BM=256) ----------------
__global__ void build_tiles_kernel(const int* __restrict__ counts, int* __restrict__ seg_off,
                                   int* __restrict__ tiles, int* __restrict__ ntiles) {
  if (blockIdx.x != 0 || threadIdx.x != 0) return;
  int off = 0, nt = 0;
  for (int e = 0; e < NE; e++) {
    seg_off[e] = off;
    int c = counts[e];
    for (int rb = 0; rb * BM < c; rb++) {
      tiles[nt * 3 + 0] = e;
      tiles[nt * 3 + 1] = off + rb * BM;
      tiles[nt * 3 + 2] = (c - rb * BM < BM) ? (c - rb * BM) : BM;
      nt++;
    }
    off += c;
  }
  seg_off[NE] = off;
  *ntiles = nt;
}

// ---------------- token assignment (+ deterministic token->slot map) ----------------
__global__ void assign_kernel(const float* __restrict__ combine, const int* __restrict__ seg_off,
                              int* __restrict__ token_flat, float* __restrict__ gate_flat,
                              int* __restrict__ tok_pos) {
  int e = blockIdx.x;
  int tid = threadIdx.x, lane = tid & 63, w = tid >> 6;
  __shared__ int base;
  __shared__ int wtot[4];
  if (tid == 0) base = seg_off[e];
  __syncthreads();
  for (int t0 = 0; t0 < NTOK; t0 += 256) {
    int t = t0 + tid;
    float g = combine[t * NE + e];
    int flag = (g > 0.0f) ? 1 : 0;
    unsigned long long m = __ballot(flag);
    if (lane == 0) wtot[w] = __popcll(m);
    __syncthreads();
    int pre = 0;
    for (int j = 0; j < w; j++) pre += wtot[j];
    int tot = wtot[0] + wtot[1] + wtot[2] + wtot[3];
    int lp = __popcll(m & ((1ull << lane) - 1ull));
    if (flag) {
      int pos = base + pre + lp;
      token_flat[pos] = t;
      gate_flat[pos] = g;
      int slot = 0;
      for (int e2 = 0; e2 < e; e2++) slot += (combine[t * NE + e2] > 0.0f) ? 1 : 0;
      if (slot < TOPK) tok_pos[t * TOPK + slot] = pos;
    }
    __syncthreads();
    if (tid == 0) base += tot;
    __syncthreads();
  }
}

// ---------------- GEMM1 fused: G = silu(X w1) * (X v1)  [R6-proven core] ----------------
__global__ __launch_bounds__(512, 4) void mlp1_kernel(
    const ushort* __restrict__ xbf, const float* __restrict__ w1, const float* __restrict__ v1,
    const int* __restrict__ tiles, const int* __restrict__ ntiles,
    const int* __restrict__ token_flat, ushort* __restrict__ G) {
  int id = blockIdx.x;
  int wg = (id & 7) * CHUNK1 + (id >> 3);
  int tile = wg % MAXT, nblk = wg / MAXT;
  if (tile >= *ntiles) return;
  const int e  = tiles[tile * 3 + 0];
  const int g0 = tiles[tile * 3 + 1];
  const int nr = tiles[tile * 3 + 2];
  const int n0 = nblk * BN;

  __shared__ __align__(16) ushort As[2][BM * BK];  // 2 x 32 KB
  __shared__ __align__(16) ushort Bw[BN * BK];     // 8 KB
  __shared__ __align__(16) ushort Bv[BN * BK];     // 8 KB

  const int tid = threadIdx.x, lane = tid & 63, wv = tid >> 6;
  const int wr = wv >> 1, wc = wv & 1;
  const int fr = lane & 15, fq = lane >> 4;

  uint aoff[4];
  int aslot[4];
  #pragma unroll
  for (int i = 0; i < 4; i++) {
    int slot = i * 512 + tid;
    int m = slot >> 3, g = slot & 7;
    int r = m < nr ? m : (nr - 1);
    int tok = token_flat[g0 + r];
    aoff[i] = (uint)(tok * HID + ((g ^ swz(m)) << 3));
    aslot[i] = slot * 8;
  }

  const int bs = tid & 255;
  const int bnq = bs & 15, bkq = bs >> 4;
  const float* bsrc = ((tid >> 8) ? v1 : w1) + (size_t)e * HID * FFN + (size_t)(bkq * 4) * FFN + n0 + bnq * 4;
  ushort* bdst = (tid >> 8) ? Bv : Bw;
  uint boff[4];
  #pragma unroll
  for (int c = 0; c < 4; c++) {
    int n = bnq * 4 + c;
    boff[c] = (uint)(n * 128 + (((bkq >> 1) ^ swz(n)) << 4) + ((bkq & 1) << 3));
  }

  float4 br0, br1, br2, br3;
  #define LOADB(k0) { size_t kb = (size_t)(k0) * FFN; \
      br0 = *(const float4*)(bsrc + kb); br1 = *(const float4*)(bsrc + kb + FFN); \
      br2 = *(const float4*)(bsrc + kb + 2 * FFN); br3 = *(const float4*)(bsrc + kb + 3 * FFN); }
  #define WRITEB() { const float* rr[4] = {(const float*)&br0, (const float*)&br1, (const float*)&br2, (const float*)&br3}; \
      _Pragma("unroll") for (int c = 0; c < 4; c++) { \
        union { ushort u[4]; uint2 v; } p; \
        _Pragma("unroll") for (int j = 0; j < 4; j++) p.u[j] = f2bf(rr[j][c]); \
        *(uint2*)((char*)bdst + boff[c]) = p.v; } }

  // prologue: stage tile 0
  LOADB(0);
  #pragma unroll
  for (int i = 0; i < 4; i++)
    gload_lds16(xbf + aoff[i], &As[0][aslot[i]]);
  WRITEB();
  __syncthreads();

  f32x4 acc_h[4][2] = {};
  f32x4 acc_v[4][2] = {};
  int cur = 0;

  for (int t = 0; t < HID / BK; t++) {
    const int last = (t == HID / BK - 1);
    if (!last) {
      int kn = (t + 1) * BK;
      LOADB(kn);
      ushort* abase = &As[cur ^ 1][0];
      #pragma unroll
      for (int i = 0; i < 4; i++)
        gload_lds16(xbf + aoff[i] + kn, abase + aslot[i]);
    }
    const char* Ab = (const char*)&As[cur][0];
    #pragma unroll
    for (int hk = 0; hk < 2; hk++) {
      bf16x8 af[4], bwf[2], bvf[2];
      #pragma unroll
      for (int am = 0; am < 4; am++) {
        int m = wr * 64 + am * 16 + fr;
        af[am] = *(const bf16x8*)(Ab + m * 128 + (((hk * 4 + fq) ^ swz(m)) << 4));
      }
      #pragma unroll
      for (int an = 0; an < 2; an++) {
        int n = wc * 32 + an * 16 + fr;
        int off = n * 128 + (((hk * 4 + fq) ^ swz(n)) << 4);
        bwf[an] = *(const bf16x8*)((const char*)Bw + off);
        bvf[an] = *(const bf16x8*)((const char*)Bv + off);
      }
      #pragma unroll
      for (int am = 0; am < 4; am++)
        #pragma unroll
        for (int an = 0; an < 2; an++) {
          acc_h[am][an] = __builtin_amdgcn_mfma_f32_16x16x32_bf16(af[am], bwf[an], acc_h[am][an], 0, 0, 0);
          acc_v[am][an] = __builtin_amdgcn_mfma_f32_16x16x32_bf16(af[am], bvf[an], acc_v[am][an], 0, 0, 0);
        }
    }
    __syncthreads();
    if (!last) { WRITEB(); }
    __syncthreads();
    cur ^= 1;
  }

  // epilogue: G = silu(h) * v
  #pragma unroll
  for (int am = 0; am < 4; am++) {
    #pragma unroll
    for (int j = 0; j < 4; j++) {
      int m = wr * 64 + am * 16 + fq * 4 + j;
      if (m < nr) {
        ushort* grow = G + (size_t)(g0 + m) * FFN + n0 + wc * 32 + fr;
        #pragma unroll
        for (int an = 0; an < 2; an++) {
          float h = acc_h[am][an][j];
          float v = acc_v[am][an][j];
          float g = h / (1.0f + __expf(-h)) * v;
          grow[an * 16] = f2bf(g);
        }
      }
    }
  }
  #undef LOADB
  #undef WRITEB
}

// ---------------- GEMM2: yscr = gate * (G w2)  [BN2=128, acc 4x4] ----------------
__global__ __launch_bounds__(512, 4) void mlp2_kernel(
    const ushort* __restrict__ G, const float* __restrict__ w2,
    const int* __restrict__ tiles, const int* __restrict__ ntiles,
    const float* __restrict__ gate_flat, ushort* __restrict__ yscr) {
  int id = blockIdx.x;
  int wg = (id & 7) * CHUNK2 + (id >> 3);
  int tile = wg % MAXT, nblk = wg / MAXT;
  if (tile >= *ntiles) return;
  const int e  = tiles[tile * 3 + 0];
  const int g0 = tiles[tile * 3 + 1];
  const int nr = tiles[tile * 3 + 2];
  const int n0 = nblk * BN2;

  __shared__ __align__(16) ushort As[2][BM * BK];   // 2 x 32 KB
  __shared__ __align__(16) ushort Bs[BN2 * BK];     // 16 KB

  const int tid = threadIdx.x, lane = tid & 63, wv = tid >> 6;
  const int wr = wv >> 1, wc = wv & 1;
  const int fr = lane & 15, fq = lane >> 4;

  uint aoff[4];
  int aslot[4];
  #pragma unroll
  for (int i = 0; i < 4; i++) {
    int slot = i * 512 + tid;
    int m = slot >> 3, g = slot & 7;
    int r = m < nr ? m : (nr - 1);
    aoff[i] = (uint)((g0 + r) * FFN + ((g ^ swz(m)) << 3));
    aslot[i] = slot * 8;
  }

  // B: 512 threads, each 4 n-cols x 4 k-rows (mlp1's proven pattern, HID stride)
  const int bnq = tid & 31, bkq = tid >> 5;  // bnq 0..31 (4 cols each), bkq 0..15 (4 k each)
  const float* bsrc = w2 + (size_t)e * FFN * HID + (size_t)(bkq * 4) * HID + n0 + bnq * 4;
  uint boff[4];
  #pragma unroll
  for (int c = 0; c < 4; c++) {
    int n = bnq * 4 + c;
    boff[c] = (uint)(n * 128 + (((bkq >> 1) ^ swz(n)) << 4) + ((bkq & 1) << 3));
  }

  float4 br0, br1, br2, br3;
  #define LOADB2(k0) { size_t kb = (size_t)(k0) * HID; \
      br0 = *(const float4*)(bsrc + kb); br1 = *(const float4*)(bsrc + kb + HID); \
      br2 = *(const float4*)(bsrc + kb + 2 * HID); br3 = *(const float4*)(bsrc + kb + 3 * HID); }
  #define WRITEB2() { const float* rr[4] = {(const float*)&br0, (const float*)&br1, (const float*)&br2, (const float*)&br3}; \
      _Pragma("unroll") for (int c = 0; c < 4; c++) { \
        union { ushort u[4]; uint2 v; } p; \
        _Pragma("unroll") for (int j = 0; j < 4; j++) p.u[j] = f2bf(rr[j][c]); \
        *(uint2*)((char*)Bs + boff[c]) = p.v; } }

  LOADB2(0);
  #pragma unroll
  for (int i = 0; i < 4; i++)
    gload_lds16(G + aoff[i], &As[0][aslot[i]]);
  WRITEB2();
  __syncthreads();

  f32x4 acc[4][4] = {};
  int cur = 0;

  for (int t = 0; t < FFN / BK; t++) {
    const int last = (t == FFN / BK - 1);
    if (!last) {
      int kn = (t + 1) * BK;
      LOADB2(kn);
      ushort* abase = &As[cur ^ 1][0];
      #pragma unroll
      for (int i = 0; i < 4; i++)
        gload_lds16(G + aoff[i] + kn, abase + aslot[i]);
    }
    const char* Ab = (const char*)&As[cur][0];
    #pragma unroll
    for (int hk = 0; hk < 2; hk++) {
      bf16x8 af[4], bf_[4];
      #pragma unroll
      for (int am = 0; am < 4; am++) {
        int m = wr * 64 + am * 16 + fr;
        af[am] = *(const bf16x8*)(Ab + m * 128 + (((hk * 4 + fq) ^ swz(m)) << 4));
      }
      #pragma unroll
      for (int an = 0; an < 4; an++) {
        int n = wc * 64 + an * 16 + fr;
        bf_[an] = *(const bf16x8*)((const char*)Bs + n * 128 + (((hk * 4 + fq) ^ swz(n)) << 4));
      }
      #pragma unroll
      for (int am = 0; am < 4; am++)
        #pragma unroll
        for (int an = 0; an < 4; an++)
          acc[am][an] = __builtin_amdgcn_mfma_f32_16x16x32_bf16(af[am], bf_[an], acc[am][an], 0, 0, 0);
    }
    __syncthreads();
    if (!last) { WRITEB2(); }
    __syncthreads();
    cur ^= 1;
  }

  #pragma unroll
  for (int am = 0; am < 4; am++) {
    #pragma unroll
    for (int j = 0; j < 4; j++) {
      int m = wr * 64 + am * 16 + fq * 4 + j;
      if (m < nr) {
        float gate = gate_flat[g0 + m];
        ushort* yrow = yscr + (size_t)(g0 + m) * HID + n0 + wc * 64 + fr;
        #pragma unroll
        for (int an = 0; an < 4; an++)
          yrow[an * 16] = f2bf(acc[am][an][j] * gate);
      }
    }
  }
  #undef LOADB2
  #undef WRITEB2
}

// ---------------- combine: out[t] = sum_k yscr[tok_pos[t][k]] ----------------
__global__ void combine_kernel(const ushort* __restrict__ yscr, const int* __restrict__ tok_pos,
                               float* __restrict__ out) {
  int t = blockIdx.x, tid = threadIdx.x;
  int c0 = tid * 8;
  float s[8] = {0.f, 0.f, 0.f, 0.f, 0.f, 0.f, 0.f, 0.f};
  #pragma unroll
  for (int k = 0; k < TOPK; k++) {
    int pos = tok_pos[t * TOPK + k];
    if (pos >= 0 && pos < TOTROWS) {
      const ushort4* yr = (const ushort4*)(yscr + (size_t)pos * HID + c0);
      ushort4 a = yr[0], b = yr[1];
      s[0] += bf2f(a.x); s[1] += bf2f(a.y); s[2] += bf2f(a.z); s[3] += bf2f(a.w);
      s[4] += bf2f(b.x); s[5] += bf2f(b.y); s[6] += bf2f(b.z); s[7] += bf2f(b.w);
    }
  }
  float4* op = (float4*)(out + (size_t)t * HID + c0);
  float4 o0 = {s[0], s[1], s[2], s[3]};
  float4 o1 = {s[4], s[5], s[6], s[7]};
  op[0] = o0; op[1] = o1;
}

// ---------------- launch ----------------
extern "C" void kernel_launch(void* const* d_in, const int* in_sizes, int n_in,
                              void* d_out, int out_size, void* d_ws, size_t ws_size,
                              hipStream_t stream) {
  const float* x  = (const float*)d_in[0];
  const float* rw = (const float*)d_in[1];
  const float* w1 = (const float*)d_in[2];
  const float* v1 = (const float*)d_in[3];
  const float* w2 = (const float*)d_in[4];
  float* out0 = (float*)d_out;
  float* wout = out0 + (size_t)NTOK * HID;

  char* ws = (char*)d_ws;
  float* combine    = (float*)(ws + 0);        // 131072 B
  int*   counts     = (int*)(ws + 131072);
  int*   seg_off    = (int*)(ws + 131200);
  int*   ntiles     = (int*)(ws + 131328);
  int*   tiles      = (int*)(ws + 131392);
  int*   token_flat = (int*)(ws + 132352);     // 32768 B
  float* gate_flat  = (float*)(ws + 165120);   // 32768 B
  int*   tok_pos    = (int*)(ws + 197888);     // 32768 B
  ushort* G         = (ushort*)(ws + 262144);                               // 64 MB
  ushort* xbf       = (ushort*)(ws + 262144 + (size_t)TOTROWS * FFN * 2);   // 8 MB
  ushort* yscr      = (ushort*)(ws + 262144 + (size_t)TOTROWS * FFN * 2
                                 + (size_t)NTOK * HID * 2);                 // 32 MB

  init_kernel<<<1, 64, 0, stream>>>(counts);
  cvt_x_kernel<<<(NTOK * HID / 4) / 256, 256, 0, stream>>>(x, (ushort*)xbf);
  router_kernel<<<NTOK, 256, 0, stream>>>(x, rw, wout, combine, counts);
  build_tiles_kernel<<<1, 1, 0, stream>>>(counts, seg_off, tiles, ntiles);
  assign_kernel<<<NE, 256, 0, stream>>>(combine, seg_off, token_flat, gate_flat, tok_pos);
  mlp1_kernel<<<GRID1, 512, 0, stream>>>(xbf, w1, v1, tiles, ntiles, token_flat, G);
  mlp2_kernel<<<GRID2, 512, 0, stream>>>(G, w2, tiles, ntiles, gate_flat, yscr);
  combine_kernel<<<NTOK, 256, 0, stream>>>(yscr, tok_pos, out0);
}